// Round 19
// baseline (123.503 us; speedup 1.0000x reference)
//
#include <hip/hip_runtime.h>

#define DMODEL 1024
#define NHEADS 16
#define DHEAD  64
#define RANK   16
#define BATCH  4
#define SEQ    1024
#define MTOT   (BATCH*SEQ)   // 4096
#define QSCALE 0.18033688011112042f  // log2(e)/8 : folded into Q projection

typedef __bf16 bf16;
typedef __bf16 bf16x8 __attribute__((ext_vector_type(8)));
typedef __bf16 bf16x4 __attribute__((ext_vector_type(4)));
typedef float  f32x4  __attribute__((ext_vector_type(4)));
typedef float  f32x16 __attribute__((ext_vector_type(16)));

// Byte-offset swizzle for LDS tiles with 128B rows (16B granules).
__device__ __forceinline__ int swz128(int row, int byte_in_row) {
  int slot = byte_in_row >> 4;
  return row * 128 + (((slot ^ (row & 7)) << 4) | (byte_in_row & 15));
}

// async global->LDS, 16B per lane. lds ptr wave-uniform; HW adds lane*16.
__device__ __forceinline__ void gll16(const void* g, void* l) {
  __builtin_amdgcn_global_load_lds((const __attribute__((address_space(1))) unsigned int*)g,
                                   (__attribute__((address_space(3))) unsigned int*)l, 16, 0, 0);
}

// pack two floats to packed bf16 pair
__device__ __forceinline__ unsigned pack2(float a, float b) {
  union { bf16 h[2]; unsigned u; } x;
  x.h[0] = (bf16)a; x.h[1] = (bf16)b;
  return x.u;
}

// swap hi-32-lanes of a with lo-32-lanes of b (both regs updated)
#define PSWAP(a, b) asm volatile("v_permlane32_swap_b32 %0, %1" : "+v"(a), "+v"(b));

// two ds_read_b64_tr_b16 with literal offsets (rule 18 fence applied by caller)
#define TRRD(lo, hi, base, o0, o1)                                   \
  asm volatile("ds_read_b64_tr_b16 %0, %2 offset:" #o0 "\n\t"        \
               "ds_read_b64_tr_b16 %1, %2 offset:" #o1               \
               : "=v"(lo), "=v"(hi) : "v"(base));

// ------- fused prologue: blocks 0..4095 prep Weff, 4096..8191 cast x --------
__global__ void prep_kernel(
    const float* __restrict__ W0, const float* __restrict__ A0, const float* __restrict__ B0,
    const float* __restrict__ W1, const float* __restrict__ A1, const float* __restrict__ B1,
    const float* __restrict__ W2, const float* __restrict__ A2, const float* __restrict__ B2,
    const float* __restrict__ W3, const float* __restrict__ A3, const float* __restrict__ B3,
    bf16* __restrict__ out, const float* __restrict__ x, bf16* __restrict__ xb) {
  __shared__ float bsc[RANK];
  const int blk = blockIdx.x;
  if (blk < 4096) {
    const int l = blk >> 10;
    const float* W = l == 0 ? W0 : l == 1 ? W1 : l == 2 ? W2 : W3;
    const float* A = l == 0 ? A0 : l == 1 ? A1 : l == 2 ? A2 : A3;
    const float* Bm = l == 0 ? B0 : l == 1 ? B1 : l == 2 ? B2 : B3;
    bf16* o = out + (size_t)l * DMODEL * DMODEL;
    const int n = blk & 1023;
    if (threadIdx.x < RANK) bsc[threadIdx.x] = Bm[threadIdx.x * DMODEL + n] * 2.0f;
    __syncthreads();
    float br[RANK];
#pragma unroll
    for (int r = 0; r < RANK; ++r) br[r] = bsc[r];
    for (int k0 = 0; k0 < DMODEL; k0 += 256) {
      int k = k0 + threadIdx.x;
      float acc = W[n * DMODEL + k];
      const float4* arow = (const float4*)(A + k * RANK);
#pragma unroll
      for (int r4 = 0; r4 < 4; ++r4) {
        float4 a = arow[r4];
        acc += a.x*br[r4*4+0] + a.y*br[r4*4+1] + a.z*br[r4*4+2] + a.w*br[r4*4+3];
      }
      o[n * DMODEL + k] = (bf16)acc;
    }
  } else {
    int i = ((blk - 4096) * 256 + threadIdx.x) * 4;
    float4 v = *(const float4*)(x + i);
    bf16x4 o4 = { (bf16)v.x, (bf16)v.y, (bf16)v.z, (bf16)v.w };
    *(bf16x4*)(xb + i) = o4;
  }
}

// QKV fused over N=3072: 128x192 tile, 8 waves (2x4 grid, 64x48 per wave).
// Grid 512 = exactly 2 blocks/CU (balanced). Outputs [b][h][s][d]; Q scaled.
__global__ __launch_bounds__(512) void gemm_qkv_kernel(
    const bf16* __restrict__ xb, const bf16* __restrict__ weff,
    const float* __restrict__ bq, const float* __restrict__ bk, const float* __restrict__ bv,
    bf16* __restrict__ Qb, bf16* __restrict__ Kb, bf16* __restrict__ Vb)
{
  __shared__ __align__(16) char sA[16384];   // 128 rows x 64 bf16
  __shared__ __align__(16) char sB[24576];   // 192 rows x 64 bf16
  const int tid = threadIdx.x, w = tid >> 6, lane = tid & 63;
  // XCD-chunked swizzle: 512 blocks -> 64 consecutive per XCD (bijective)
  const int bid = blockIdx.x;
  const int nb = (bid & 7) * 64 + (bid >> 3);
  const int n0 = (nb & 15) * 192, m0 = (nb >> 4) * 128;
  const int wm = (w & 1) * 64, wn = (w >> 1) * 48;
  f32x4 acc[4][3] = {};

  const bf16* pA[2]; const bf16* pB[3]; char* lA[2]; char* lB[3];
#pragma unroll
  for (int i = 0; i < 2; ++i) {
    int ci = i * 8 + w;
    int row = ci * 8 + (lane >> 3);
    int ss = (lane & 7) ^ (row & 7);
    pA[i] = xb + (size_t)(m0 + row) * DMODEL + ss * 8;
    lA[i] = sA + ci * 1024;
  }
#pragma unroll
  for (int i = 0; i < 3; ++i) {
    int ci = i * 8 + w;
    int row = ci * 8 + (lane >> 3);
    int ss = (lane & 7) ^ (row & 7);
    pB[i] = weff + (size_t)(n0 + row) * DMODEL + ss * 8;
    lB[i] = sB + ci * 1024;
  }
  for (int kt = 0; kt < DMODEL / 64; ++kt) {
    const int kbase = kt * 64;
#pragma unroll
    for (int i = 0; i < 2; ++i) gll16(pA[i] + kbase, lA[i]);
#pragma unroll
    for (int i = 0; i < 3; ++i) gll16(pB[i] + kbase, lB[i]);
    __syncthreads();
#pragma unroll
    for (int ks = 0; ks < 2; ++ks) {
      bf16x8 af[4], bfg[3];
#pragma unroll
      for (int mi = 0; mi < 4; ++mi)
        af[mi] = *(const bf16x8*)(sA + swz128(wm + mi*16 + (lane & 15), ks*64 + (lane >> 4)*16));
#pragma unroll
      for (int ni = 0; ni < 3; ++ni)
        bfg[ni] = *(const bf16x8*)(sB + swz128(wn + ni*16 + (lane & 15), ks*64 + (lane >> 4)*16));
#pragma unroll
      for (int mi = 0; mi < 4; ++mi)
#pragma unroll
        for (int ni = 0; ni < 3; ++ni)
          acc[mi][ni] = __builtin_amdgcn_mfma_f32_16x16x32_bf16(af[mi], bfg[ni], acc[mi][ni], 0, 0, 0);
    }
    __syncthreads();
  }

  // Epilogue: 16-aligned fragment never straddles a 1024 boundary -> per-ni z.
#pragma unroll
  for (int mi = 0; mi < 4; ++mi) {
#pragma unroll
    for (int ni = 0; ni < 3; ++ni) {
      int col = n0 + wn + ni * 16 + (lane & 15);      // global over 3072
      int zc = col >> 10;
      const float* bz = zc == 0 ? bq : (zc == 1 ? bk : bv);
      bf16* outp = zc == 0 ? Qb : (zc == 1 ? Kb : Vb);
      float scl = zc == 0 ? QSCALE : 1.0f;
      float bcol = bz[col & 1023];
      int h = (col >> 6) & 15, d = col & 63;
#pragma unroll
      for (int r = 0; r < 4; ++r) {
        int row = m0 + wm + mi * 16 + (lane >> 4) * 4 + r;
        float v = (acc[mi][ni][r] + bcol) * scl;
        int b = row >> 10, s = row & 1023;
        outp[(size_t)((b * NHEADS + h) * SEQ + s) * DHEAD + d] = (bf16)v;
      }
    }
  }
}

// -------- flash attention: 32x32 swapped-QK, in-register P via permlane -----
// KVBLK=128 (two 64-key halves per k-tile). lsum via ones-MFMA (C-layout).
// 4 waves x 32q = QBLK 128; grid 512 (2 blocks/CU; LDS 64KB dbuf).
__global__ __launch_bounds__(256) void flash_kernel(
    const bf16* __restrict__ Qb, const bf16* __restrict__ Kb, const bf16* __restrict__ Vb,
    bf16* __restrict__ ctx, float* __restrict__ lstat)
{
  __shared__ __align__(16) char sK[2 * 16384];  // dbuf [128 key][128B d] swizzled
  __shared__ __align__(16) char sV[2 * 16384];  // dbuf subtiled [k/4][d/16][4][16]
  const int tid = threadIdx.x, w = tid >> 6, lane = tid & 63;
  const int l31 = lane & 31, lh = lane >> 5;
  const int bid = blockIdx.x;
  const int nb = (bid & 7) * 64 + (bid >> 3);
  const int bh = nb >> 3;
  const int q0 = (nb & 7) * 128;
  const bf16* Qbase = Qb + (size_t)bh * SEQ * DHEAD;
  const bf16* Kbase = Kb + (size_t)bh * SEQ * DHEAD;
  const bf16* Vbase = Vb + (size_t)bh * SEQ * DHEAD;
  const int qw = q0 + w * 32;

  // Q fragments (B-operand): lane l -> Q[q=qw+l31][kd = kb*16 + lh*8 + j]
  bf16x8 aq[4];
#pragma unroll
  for (int kb = 0; kb < 4; ++kb)
    aq[kb] = *(const bf16x8*)(Qbase + (size_t)(qw + l31) * DHEAD + kb * 16 + lh * 8);

  // ones B-fragment for row-sum MFMA
  bf16x8 onesf;
#pragma unroll
  for (int j = 0; j < 8; ++j) onesf[j] = (bf16)1.0f;

  // staging: wave stages chunks {w, w+4, w+8, w+12} for K and V.
  const bf16* pK0; const bf16* pV0; int lKo0, lVo0;
  {
    int rowK = w * 8 + (lane >> 3);
    int ssK = (lane & 7) ^ (rowK & 7);
    pK0 = Kbase + (size_t)rowK * DHEAD + ssK * 8;   // + kt*128*DHEAD
    lKo0 = w * 1024;
    int kV = w * 8 + ((lane >> 5) & 1) * 4 + ((lane >> 1) & 3);
    int dV = (((lane >> 3) & 3) << 4) + ((lane & 1) << 3);
    pV0 = Vbase + (size_t)kV * DHEAD + dV;          // + kt*128*DHEAD
    lVo0 = w * 1024;
  }

  // V tr-read base (validated): per-lane = lh*1024 + bit4*128 + (l&15)*8
  const unsigned vb0 = (unsigned)(uintptr_t)sV + lh * 1024 + ((lane >> 4) & 1) * 128
                       + (lane & 15) * 8;

  f32x16 oacc[2] = {};
  f32x16 lacc = {};

  // prologue: stage k-tile 0 (128 keys) into buffer 0
#pragma unroll
  for (int i = 0; i < 4; ++i) {
    gll16(pK0 + (size_t)i * 32 * DHEAD, sK + lKo0 + i * 4096);
    gll16(pV0 + (size_t)i * 32 * DHEAD, sV + lVo0 + i * 4096);
  }
  __syncthreads();

  for (int kt = 0; kt < SEQ / 128; ++kt) {
    const int cur = (kt & 1) << 14, nxt = cur ^ 16384;
    if (kt + 1 < SEQ / 128) {     // prefetch next 128-key tile
      const size_t kofs = (size_t)(kt + 1) * 128 * DHEAD;
#pragma unroll
      for (int i = 0; i < 4; ++i) {
        gll16(pK0 + kofs + (size_t)i * 32 * DHEAD, sK + nxt + lKo0 + i * 4096);
        gll16(pV0 + kofs + (size_t)i * 32 * DHEAD, sV + nxt + lVo0 + i * 4096);
      }
    }

#pragma unroll
    for (int half = 0; half < 2; ++half) {
      const int hb_ = cur + half * 8192;
      // swapped QK^T: S^T C-layout col q=l31, row key=(r&3)+8(r>>2)+4lh (+32ksb)
      f32x16 s[2] = {};
      __builtin_amdgcn_s_setprio(1);
#pragma unroll
      for (int ksb = 0; ksb < 2; ++ksb)
#pragma unroll
        for (int kb = 0; kb < 4; ++kb) {
          bf16x8 ak = *(const bf16x8*)(sK + hb_ + swz128(ksb*32 + l31, kb*32 + lh*16));
          s[ksb] = __builtin_amdgcn_mfma_f32_32x32x16_bf16(ak, aq[kb], s[ksb], 0, 0, 0);
        }
      __builtin_amdgcn_s_setprio(0);

      // issue all 16 V transpose-reads (latency hides under softmax VALU)
      unsigned long long v0[4][2], v1[4][2];   // [kbg][db]
      const unsigned vb = vb0 + hb_;
      TRRD(v0[0][0], v1[0][0], vb, 0, 512)
      TRRD(v0[0][1], v1[0][1], vb, 256, 768)
      TRRD(v0[1][0], v1[1][0], vb, 2048, 2560)
      TRRD(v0[1][1], v1[1][1], vb, 2304, 2816)
      TRRD(v0[2][0], v1[2][0], vb, 4096, 4608)
      TRRD(v0[2][1], v1[2][1], vb, 4352, 4864)
      TRRD(v0[3][0], v1[3][0], vb, 6144, 6656)
      TRRD(v0[3][1], v1[3][1], vb, 6400, 6912)

      // P = exp2(S^T); build PV A-fragments in-register via permlane32_swap
      bf16x8 paf[4];
#pragma unroll
      for (int ksb = 0; ksb < 2; ++ksb) {
        float p[16];
#pragma unroll
        for (int r = 0; r < 16; ++r)
          p[r] = __builtin_amdgcn_exp2f(s[ksb][r]);
        unsigned a0 = pack2(p[0], p[1]),   b0 = pack2(p[4], p[5]);
        unsigned a1 = pack2(p[2], p[3]),   b1 = pack2(p[6], p[7]);
        PSWAP(a0, b0) PSWAP(a1, b1)
        unsigned c0 = pack2(p[8], p[9]),   d0 = pack2(p[12], p[13]);
        unsigned c1 = pack2(p[10], p[11]), d1 = pack2(p[14], p[15]);
        PSWAP(c0, d0) PSWAP(c1, d1)
        union { unsigned u[4]; bf16x8 v; } A0, A1;
        A0.u[0] = a0; A0.u[1] = a1; A0.u[2] = b0; A0.u[3] = b1;
        A1.u[0] = c0; A1.u[1] = c1; A1.u[2] = d0; A1.u[3] = d1;
        paf[ksb * 2 + 0] = A0.v;
        paf[ksb * 2 + 1] = A1.v;
      }

      asm volatile("s_waitcnt lgkmcnt(0)" ::: "memory");
      __builtin_amdgcn_sched_barrier(0);

      // PV: O[q][d] += P[q][key] * V[key][d]; lacc += P row-sums (ones-MFMA)
      __builtin_amdgcn_s_setprio(1);
#pragma unroll
      for (int kbg = 0; kbg < 4; ++kbg) {
#pragma unroll
        for (int db = 0; db < 2; ++db) {
          union { unsigned long long u[2]; bf16x8 v; } V;
          V.u[0] = v0[kbg][db]; V.u[1] = v1[kbg][db];
          oacc[db] = __builtin_amdgcn_mfma_f32_32x32x16_bf16(paf[kbg], V.v, oacc[db], 0, 0, 0);
        }
        lacc = __builtin_amdgcn_mfma_f32_32x32x16_bf16(paf[kbg], onesf, lacc, 0, 0, 0);
      }
      __builtin_amdgcn_s_setprio(0);
    }
    __syncthreads();   // drains prefetch vmcnt + publishes next buffer
  }

  // lacc[r] = full row-sum for q=q_r in the SAME C-layout as oacc -> no shfl.
  const int b = bh >> 4, hh = bh & 15;
#pragma unroll
  for (int r = 0; r < 16; ++r) {
    int q_r = (r & 3) + 8 * (r >> 2) + 4 * lh;
    float inv = __builtin_amdgcn_rcpf(lacc[r]);
    int row = qw + q_r;
#pragma unroll
    for (int db = 0; db < 2; ++db)
      ctx[(size_t)(b * SEQ + row) * DMODEL + hh * DHEAD + db * 32 + l31] =
          (bf16)(oacc[db][r] * inv);
  }
  if (l31 == 0) {
#pragma unroll
    for (int r = 0; r < 16; ++r) {
      int q_r = (r & 3) + 8 * (r >> 2) + 4 * lh;
      lstat[(size_t)bh * SEQ + qw + q_r] = lacc[r];
    }
  }
}

// ------- fused tail: blocks 0..255 mean (128q x 128k, head-dbuf),          --
// -------             blocks 256..767 gemm_o (64x128 + residual)            --
// Mean QT=128 halves K re-read traffic (134->67 MB) vs QT=64.
__global__ __launch_bounds__(256) void tail_kernel(
    const bf16* __restrict__ Qb, const bf16* __restrict__ Kb,
    const float* __restrict__ lstat, float* __restrict__ out2,
    const bf16* __restrict__ ctx, const bf16* __restrict__ weffo,
    const float* __restrict__ bias, const float* __restrict__ resid,
    float* __restrict__ outf)
{
  __shared__ __align__(16) char smem[2 * 16384];
  const int tid = threadIdx.x, w = tid >> 6, lane = tid & 63;

  if (blockIdx.x < 256) {
    // ------------ mean path: 128q x 128k, wave owns 32 q-rows -------------
    char* sK = smem;
    const int bid = blockIdx.x;
    const int nb2 = (bid & 7) * 32 + (bid >> 3);   // XCD-chunked, 256 blocks
    const int b = nb2 >> 6;
    const int q0 = ((nb2 >> 3) & 7) * 128, k0 = (nb2 & 7) * 128;
    const int qw = q0 + w * 32;
    size_t goff[4]; int lofs[4];
#pragma unroll
    for (int i = 0; i < 4; ++i) {
      int chunk = i * 4 + w;
      int row = chunk * 8 + (lane >> 3);
      int ss = (lane & 7) ^ (row & 7);
      goff[i] = (size_t)(k0 + row) * DHEAD + ss * 8;
      lofs[i] = chunk * 1024;
    }
    const bf16* Kb_b = Kb + (size_t)b * NHEADS * SEQ * DHEAD;
    const bf16* Qb_b = Qb + (size_t)b * NHEADS * SEQ * DHEAD;

    f32x4 macc[2][8] = {};
#pragma unroll
    for (int i = 0; i < 4; ++i) gll16(Kb_b + goff[i], sK + lofs[i]);
    asm volatile("s_waitcnt vmcnt(0)" ::: "memory");
    __syncthreads();

    for (int h = 0; h < NHEADS; ++h) {
      const int cur = (h & 1) << 14, nxt = cur ^ 16384;
      if (h + 1 < NHEADS) {
        const bf16* Kn = Kb_b + (size_t)(h + 1) * SEQ * DHEAD;
#pragma unroll
        for (int i = 0; i < 4; ++i) gll16(Kn + goff[i], sK + nxt + lofs[i]);
      }
      const bf16* Qbase = Qb_b + (size_t)h * SEQ * DHEAD;
      bf16x8 aq[2][2];
#pragma unroll
      for (int mi = 0; mi < 2; ++mi)
#pragma unroll
        for (int ks = 0; ks < 2; ++ks)
          aq[mi][ks] = *(const bf16x8*)(Qbase + (size_t)(qw + mi*16 + (lane & 15)) * DHEAD
                                        + ks * 32 + (lane >> 4) * 8);
      char* cK = sK + cur;
      f32x4 sc[2][8] = {};
#pragma unroll
      for (int ks = 0; ks < 2; ++ks)
#pragma unroll
        for (int ni = 0; ni < 8; ++ni) {
          bf16x8 bk = *(const bf16x8*)(cK + swz128(ni*16 + (lane & 15), ks*64 + (lane >> 4)*16));
#pragma unroll
          for (int mi = 0; mi < 2; ++mi)
            sc[mi][ni] = __builtin_amdgcn_mfma_f32_16x16x32_bf16(aq[mi][ks], bk, sc[mi][ni], 0, 0, 0);
        }
      float lsc[2][4];
      const float* ls = lstat + ((size_t)(b * NHEADS + h)) * SEQ;
#pragma unroll
      for (int mi = 0; mi < 2; ++mi)
#pragma unroll
        for (int r = 0; r < 4; ++r)
          lsc[mi][r] = 0.0625f * __builtin_amdgcn_rcpf(ls[qw + mi*16 + (lane >> 4)*4 + r]);
#pragma unroll
      for (int mi = 0; mi < 2; ++mi)
#pragma unroll
        for (int ni = 0; ni < 8; ++ni)
#pragma unroll
          for (int r = 0; r < 4; ++r)
            macc[mi][ni][r] += __builtin_amdgcn_exp2f(sc[mi][ni][r]) * lsc[mi][r];
      asm volatile("s_waitcnt vmcnt(0)" ::: "memory");
      __syncthreads();
    }
#pragma unroll
    for (int mi = 0; mi < 2; ++mi)
#pragma unroll
      for (int r = 0; r < 4; ++r) {
        int qrow = qw + mi*16 + (lane >> 4) * 4 + r;
#pragma unroll
        for (int ni = 0; ni < 8; ++ni)
          out2[(size_t)(b * SEQ + qrow) * SEQ + k0 + ni * 16 + (lane & 15)] = macc[mi][ni][r];
      }
  } else {
    // ---------------- gemm_o path ----------------
    char* sA = smem; char* sB = smem + 8192;
    const int bid = blockIdx.x - 256;              // 512 blocks
    const int nb = (bid & 7) * 64 + (bid >> 3);
    const int n0 = (nb & 7) * 128, m0 = (nb >> 3) * 64;
    const int wm = (w & 1) * 32, wn = (w >> 1) * 64;
    f32x4 acc[2][4] = {};
    const bf16* pA[2]; char* lA[2];
    const bf16* pB[4]; char* lB[4];
#pragma unroll
    for (int i = 0; i < 2; ++i) {
      int chunk = i * 4 + w;
      int row = chunk * 8 + (lane >> 3);
      int ss = (lane & 7) ^ (row & 7);
      pA[i] = ctx + (size_t)(m0 + row) * DMODEL + ss * 8;
      lA[i] = sA + chunk * 1024;
    }
#pragma unroll
    for (int i = 0; i < 4; ++i) {
      int chunk = i * 4 + w;
      int row = chunk * 8 + (lane >> 3);
      int ss = (lane & 7) ^ (row & 7);
      pB[i] = weffo + (size_t)(n0 + row) * DMODEL + ss * 8;
      lB[i] = sB + chunk * 1024;
    }
    for (int kt = 0; kt < DMODEL / 64; ++kt) {
      const int kbase = kt * 64;
#pragma unroll
      for (int i = 0; i < 2; ++i) gll16(pA[i] + kbase, lA[i]);
#pragma unroll
      for (int i = 0; i < 4; ++i) gll16(pB[i] + kbase, lB[i]);
      __syncthreads();
#pragma unroll
      for (int ks = 0; ks < 2; ++ks) {
        bf16x8 af[2], bfg[4];
#pragma unroll
        for (int mi = 0; mi < 2; ++mi)
          af[mi] = *(const bf16x8*)(sA + swz128(wm + mi*16 + (lane & 15), ks*64 + (lane >> 4)*16));
#pragma unroll
        for (int ni = 0; ni < 4; ++ni)
          bfg[ni] = *(const bf16x8*)(sB + swz128(wn + ni*16 + (lane & 15), ks*64 + (lane >> 4)*16));
#pragma unroll
        for (int mi = 0; mi < 2; ++mi)
#pragma unroll
          for (int ni = 0; ni < 4; ++ni)
            acc[mi][ni] = __builtin_amdgcn_mfma_f32_16x16x32_bf16(af[mi], bfg[ni], acc[mi][ni], 0, 0, 0);
      }
      __syncthreads();
    }
#pragma unroll
    for (int mi = 0; mi < 2; ++mi) {
#pragma unroll
      for (int ni = 0; ni < 4; ++ni) {
        int col = n0 + wn + ni * 16 + (lane & 15);
        float bcol = bias[col];
#pragma unroll
        for (int r = 0; r < 4; ++r) {
          int row = m0 + wm + mi * 16 + (lane >> 4) * 4 + r;
          outf[(size_t)row * DMODEL + col] =
              acc[mi][ni][r] + bcol + resid[(size_t)row * DMODEL + col];
        }
      }
    }
  }
}

// ---------------- residual LayerNorm (in-place on fp32 rows) ----------------
__global__ __launch_bounds__(256) void ln_kernel(
    float* __restrict__ hb, const float* __restrict__ g,
    const float* __restrict__ bvec, float* __restrict__ out)
{
  const int row = blockIdx.x, t = threadIdx.x;
  float4 v = *(const float4*)(hb + (size_t)row * DMODEL + t * 4);
  float s = v.x + v.y + v.z + v.w;
  float s2 = v.x*v.x + v.y*v.y + v.z*v.z + v.w*v.w;
#pragma unroll
  for (int off = 32; off >= 1; off >>= 1) {
    s  += __shfl_down(s, off);
    s2 += __shfl_down(s2, off);
  }
  __shared__ float red[8];
  const int w = t >> 6;
  if ((t & 63) == 0) { red[w] = s; red[4 + w] = s2; }
  __syncthreads();
  if (t == 0) {
    red[0] = red[0] + red[1] + red[2] + red[3];
    red[4] = red[4] + red[5] + red[6] + red[7];
  }
  __syncthreads();
  float mu = red[0] * (1.0f / DMODEL);
  float var = red[4] * (1.0f / DMODEL) - mu * mu;
  float rs = rsqrtf(var + 1e-5f);
  float4 gv = *(const float4*)(g + t * 4);
  float4 bv = *(const float4*)(bvec + t * 4);
  float4 o;
  o.x = (v.x - mu) * rs * gv.x + bv.x;
  o.y = (v.y - mu) * rs * gv.y + bv.y;
  o.z = (v.z - mu) * rs * gv.z + bv.z;
  o.w = (v.w - mu) * rs * gv.w + bv.w;
  *(float4*)(out + (size_t)row * DMODEL + t * 4) = o;
}

extern "C" void kernel_launch(void* const* d_in, const int* in_sizes, int n_in,
                              void* d_out, int out_size, void* d_ws, size_t ws_size,
                              hipStream_t stream) {
  (void)in_sizes; (void)n_in; (void)out_size; (void)ws_size;
  const float* x = (const float*)d_in[0];
  const float* w_[4]  = {(const float*)d_in[1],  (const float*)d_in[5],
                         (const float*)d_in[9],  (const float*)d_in[13]};
  const float* b_[4]  = {(const float*)d_in[2],  (const float*)d_in[6],
                         (const float*)d_in[10], (const float*)d_in[14]};
  const float* A_[4]  = {(const float*)d_in[3],  (const float*)d_in[7],
                         (const float*)d_in[11], (const float*)d_in[15]};
  const float* Bm_[4] = {(const float*)d_in[4],  (const float*)d_in[8],
                         (const float*)d_in[12], (const float*)d_in[16]};
  const float* lng = (const float*)d_in[17];
  const float* lnb = (const float*)d_in[18];

  char* ws = (char*)d_ws;
  bf16* xb    = (bf16*)(ws);                         // 8MB, reused as ctx later
  bf16* weff  = (bf16*)(ws + (8u  << 20));           // 4 x 2MB (q|k|v|o contiguous)
  bf16* Qb    = (bf16*)(ws + (16u << 20));           // 8MB [b][h][s][d] (pre-scaled)
  bf16* Kb    = (bf16*)(ws + (24u << 20));           // 8MB [b][h][s][d]
  bf16* Vb    = (bf16*)(ws + (32u << 20));           // 8MB [b][h][s][d]
  float* lstat = (float*)(ws + (40u << 20));         // 256KB
  bf16* ctx = xb;                    // alias: xb dead after QKV projections
  float* hbuf = (float*)d_out;       // fp32 scratch = output slot 0 (in-place LN)
  float* out2 = (float*)d_out + (size_t)MTOT * DMODEL;

  prep_kernel<<<dim3(8192), dim3(256), 0, stream>>>(
      w_[0], A_[0], Bm_[0], w_[1], A_[1], Bm_[1],
      w_[2], A_[2], Bm_[2], w_[3], A_[3], Bm_[3], weff, x, xb);

  gemm_qkv_kernel<<<dim3(512), 512, 0, stream>>>(
      xb, weff, b_[0], b_[1], b_[2], Qb, Kb, Vb);

  flash_kernel<<<dim3(512), 256, 0, stream>>>(Qb, Kb, Vb, ctx, lstat);

  tail_kernel<<<dim3(768), 256, 0, stream>>>(
      Qb, Kb, lstat, out2,
      ctx, weff + 3u * DMODEL * DMODEL, b_[3], x, hbuf);

  ln_kernel<<<dim3(MTOT), 256, 0, stream>>>(hbuf, lng, lnb, hbuf);
}

// Round 20
// 120.288 us; speedup vs baseline: 1.0267x; 1.0267x over previous
//
#include <hip/hip_runtime.h>

#define DMODEL 1024
#define NHEADS 16
#define DHEAD  64
#define RANK   16
#define BATCH  4
#define SEQ    1024
#define MTOT   (BATCH*SEQ)   // 4096
#define QSCALE 0.18033688011112042f  // log2(e)/8 : folded into Q projection

typedef __bf16 bf16;
typedef __bf16 bf16x8 __attribute__((ext_vector_type(8)));
typedef __bf16 bf16x4 __attribute__((ext_vector_type(4)));
typedef float  f32x4  __attribute__((ext_vector_type(4)));
typedef float  f32x16 __attribute__((ext_vector_type(16)));

// Byte-offset swizzle for LDS tiles with 128B rows (16B granules).
__device__ __forceinline__ int swz128(int row, int byte_in_row) {
  int slot = byte_in_row >> 4;
  return row * 128 + (((slot ^ (row & 7)) << 4) | (byte_in_row & 15));
}

// async global->LDS, 16B per lane. lds ptr wave-uniform; HW adds lane*16.
__device__ __forceinline__ void gll16(const void* g, void* l) {
  __builtin_amdgcn_global_load_lds((const __attribute__((address_space(1))) unsigned int*)g,
                                   (__attribute__((address_space(3))) unsigned int*)l, 16, 0, 0);
}

// pack two floats to packed bf16 pair
__device__ __forceinline__ unsigned pack2(float a, float b) {
  union { bf16 h[2]; unsigned u; } x;
  x.h[0] = (bf16)a; x.h[1] = (bf16)b;
  return x.u;
}

// swap hi-32-lanes of a with lo-32-lanes of b (both regs updated)
#define PSWAP(a, b) asm volatile("v_permlane32_swap_b32 %0, %1" : "+v"(a), "+v"(b));

// two ds_read_b64_tr_b16 with literal offsets (rule 18 fence applied by caller)
#define TRRD(lo, hi, base, o0, o1)                                   \
  asm volatile("ds_read_b64_tr_b16 %0, %2 offset:" #o0 "\n\t"        \
               "ds_read_b64_tr_b16 %1, %2 offset:" #o1               \
               : "=v"(lo), "=v"(hi) : "v"(base));

// ------- fused prologue: blocks 0..4095 prep Weff, 4096..8191 cast x --------
__global__ void prep_kernel(
    const float* __restrict__ W0, const float* __restrict__ A0, const float* __restrict__ B0,
    const float* __restrict__ W1, const float* __restrict__ A1, const float* __restrict__ B1,
    const float* __restrict__ W2, const float* __restrict__ A2, const float* __restrict__ B2,
    const float* __restrict__ W3, const float* __restrict__ A3, const float* __restrict__ B3,
    bf16* __restrict__ out, const float* __restrict__ x, bf16* __restrict__ xb) {
  __shared__ float bsc[RANK];
  const int blk = blockIdx.x;
  if (blk < 4096) {
    const int l = blk >> 10;
    const float* W = l == 0 ? W0 : l == 1 ? W1 : l == 2 ? W2 : W3;
    const float* A = l == 0 ? A0 : l == 1 ? A1 : l == 2 ? A2 : A3;
    const float* Bm = l == 0 ? B0 : l == 1 ? B1 : l == 2 ? B2 : B3;
    bf16* o = out + (size_t)l * DMODEL * DMODEL;
    const int n = blk & 1023;
    if (threadIdx.x < RANK) bsc[threadIdx.x] = Bm[threadIdx.x * DMODEL + n] * 2.0f;
    __syncthreads();
    float br[RANK];
#pragma unroll
    for (int r = 0; r < RANK; ++r) br[r] = bsc[r];
    for (int k0 = 0; k0 < DMODEL; k0 += 256) {
      int k = k0 + threadIdx.x;
      float acc = W[n * DMODEL + k];
      const float4* arow = (const float4*)(A + k * RANK);
#pragma unroll
      for (int r4 = 0; r4 < 4; ++r4) {
        float4 a = arow[r4];
        acc += a.x*br[r4*4+0] + a.y*br[r4*4+1] + a.z*br[r4*4+2] + a.w*br[r4*4+3];
      }
      o[n * DMODEL + k] = (bf16)acc;
    }
  } else {
    int i = ((blk - 4096) * 256 + threadIdx.x) * 4;
    float4 v = *(const float4*)(x + i);
    bf16x4 o4 = { (bf16)v.x, (bf16)v.y, (bf16)v.z, (bf16)v.w };
    *(bf16x4*)(xb + i) = o4;
  }
}

// QKV fused over N=3072: 128x192 tile, 8 waves (2x4 grid, 64x48 per wave).
// Grid 512 = exactly 2 blocks/CU (balanced). Outputs [b][h][s][d]; Q scaled.
__global__ __launch_bounds__(512) void gemm_qkv_kernel(
    const bf16* __restrict__ xb, const bf16* __restrict__ weff,
    const float* __restrict__ bq, const float* __restrict__ bk, const float* __restrict__ bv,
    bf16* __restrict__ Qb, bf16* __restrict__ Kb, bf16* __restrict__ Vb)
{
  __shared__ __align__(16) char sA[16384];   // 128 rows x 64 bf16
  __shared__ __align__(16) char sB[24576];   // 192 rows x 64 bf16
  const int tid = threadIdx.x, w = tid >> 6, lane = tid & 63;
  // XCD-chunked swizzle: 512 blocks -> 64 consecutive per XCD (bijective)
  const int bid = blockIdx.x;
  const int nb = (bid & 7) * 64 + (bid >> 3);
  const int n0 = (nb & 15) * 192, m0 = (nb >> 4) * 128;
  const int wm = (w & 1) * 64, wn = (w >> 1) * 48;
  f32x4 acc[4][3] = {};

  const bf16* pA[2]; const bf16* pB[3]; char* lA[2]; char* lB[3];
#pragma unroll
  for (int i = 0; i < 2; ++i) {
    int ci = i * 8 + w;
    int row = ci * 8 + (lane >> 3);
    int ss = (lane & 7) ^ (row & 7);
    pA[i] = xb + (size_t)(m0 + row) * DMODEL + ss * 8;
    lA[i] = sA + ci * 1024;
  }
#pragma unroll
  for (int i = 0; i < 3; ++i) {
    int ci = i * 8 + w;
    int row = ci * 8 + (lane >> 3);
    int ss = (lane & 7) ^ (row & 7);
    pB[i] = weff + (size_t)(n0 + row) * DMODEL + ss * 8;
    lB[i] = sB + ci * 1024;
  }
  for (int kt = 0; kt < DMODEL / 64; ++kt) {
    const int kbase = kt * 64;
#pragma unroll
    for (int i = 0; i < 2; ++i) gll16(pA[i] + kbase, lA[i]);
#pragma unroll
    for (int i = 0; i < 3; ++i) gll16(pB[i] + kbase, lB[i]);
    __syncthreads();
#pragma unroll
    for (int ks = 0; ks < 2; ++ks) {
      bf16x8 af[4], bfg[3];
#pragma unroll
      for (int mi = 0; mi < 4; ++mi)
        af[mi] = *(const bf16x8*)(sA + swz128(wm + mi*16 + (lane & 15), ks*64 + (lane >> 4)*16));
#pragma unroll
      for (int ni = 0; ni < 3; ++ni)
        bfg[ni] = *(const bf16x8*)(sB + swz128(wn + ni*16 + (lane & 15), ks*64 + (lane >> 4)*16));
#pragma unroll
      for (int mi = 0; mi < 4; ++mi)
#pragma unroll
        for (int ni = 0; ni < 3; ++ni)
          acc[mi][ni] = __builtin_amdgcn_mfma_f32_16x16x32_bf16(af[mi], bfg[ni], acc[mi][ni], 0, 0, 0);
    }
    __syncthreads();
  }

  // Epilogue: 16-aligned fragment never straddles a 1024 boundary -> per-ni z.
#pragma unroll
  for (int mi = 0; mi < 4; ++mi) {
#pragma unroll
    for (int ni = 0; ni < 3; ++ni) {
      int col = n0 + wn + ni * 16 + (lane & 15);      // global over 3072
      int zc = col >> 10;
      const float* bz = zc == 0 ? bq : (zc == 1 ? bk : bv);
      bf16* outp = zc == 0 ? Qb : (zc == 1 ? Kb : Vb);
      float scl = zc == 0 ? QSCALE : 1.0f;
      float bcol = bz[col & 1023];
      int h = (col >> 6) & 15, d = col & 63;
#pragma unroll
      for (int r = 0; r < 4; ++r) {
        int row = m0 + wm + mi * 16 + (lane >> 4) * 4 + r;
        float v = (acc[mi][ni][r] + bcol) * scl;
        int b = row >> 10, s = row & 1023;
        outp[(size_t)((b * NHEADS + h) * SEQ + s) * DHEAD + d] = (bf16)v;
      }
    }
  }
}

// -------- flash attention: 32x32 swapped-QK, in-register P via permlane -----
// KVBLK=128 (two 64-key halves per k-tile). lsum via ones-MFMA (C-layout).
// 4 waves x 32q = QBLK 128; grid 512 (2 blocks/CU; LDS 64KB dbuf).
__global__ __launch_bounds__(256) void flash_kernel(
    const bf16* __restrict__ Qb, const bf16* __restrict__ Kb, const bf16* __restrict__ Vb,
    bf16* __restrict__ ctx, float* __restrict__ lstat)
{
  __shared__ __align__(16) char sK[2 * 16384];  // dbuf [128 key][128B d] swizzled
  __shared__ __align__(16) char sV[2 * 16384];  // dbuf subtiled [k/4][d/16][4][16]
  const int tid = threadIdx.x, w = tid >> 6, lane = tid & 63;
  const int l31 = lane & 31, lh = lane >> 5;
  const int bid = blockIdx.x;
  const int nb = (bid & 7) * 64 + (bid >> 3);
  const int bh = nb >> 3;
  const int q0 = (nb & 7) * 128;
  const bf16* Qbase = Qb + (size_t)bh * SEQ * DHEAD;
  const bf16* Kbase = Kb + (size_t)bh * SEQ * DHEAD;
  const bf16* Vbase = Vb + (size_t)bh * SEQ * DHEAD;
  const int qw = q0 + w * 32;

  // Q fragments (B-operand): lane l -> Q[q=qw+l31][kd = kb*16 + lh*8 + j]
  bf16x8 aq[4];
#pragma unroll
  for (int kb = 0; kb < 4; ++kb)
    aq[kb] = *(const bf16x8*)(Qbase + (size_t)(qw + l31) * DHEAD + kb * 16 + lh * 8);

  // ones B-fragment for row-sum MFMA
  bf16x8 onesf;
#pragma unroll
  for (int j = 0; j < 8; ++j) onesf[j] = (bf16)1.0f;

  // staging: wave stages chunks {w, w+4, w+8, w+12} for K and V.
  const bf16* pK0; const bf16* pV0; int lKo0, lVo0;
  {
    int rowK = w * 8 + (lane >> 3);
    int ssK = (lane & 7) ^ (rowK & 7);
    pK0 = Kbase + (size_t)rowK * DHEAD + ssK * 8;   // + kt*128*DHEAD
    lKo0 = w * 1024;
    int kV = w * 8 + ((lane >> 5) & 1) * 4 + ((lane >> 1) & 3);
    int dV = (((lane >> 3) & 3) << 4) + ((lane & 1) << 3);
    pV0 = Vbase + (size_t)kV * DHEAD + dV;          // + kt*128*DHEAD
    lVo0 = w * 1024;
  }

  // V tr-read base (validated): per-lane = lh*1024 + bit4*128 + (l&15)*8
  const unsigned vb0 = (unsigned)(uintptr_t)sV + lh * 1024 + ((lane >> 4) & 1) * 128
                       + (lane & 15) * 8;

  f32x16 oacc[2] = {};
  f32x16 lacc = {};

  // prologue: stage k-tile 0 (128 keys) into buffer 0
#pragma unroll
  for (int i = 0; i < 4; ++i) {
    gll16(pK0 + (size_t)i * 32 * DHEAD, sK + lKo0 + i * 4096);
    gll16(pV0 + (size_t)i * 32 * DHEAD, sV + lVo0 + i * 4096);
  }
  __syncthreads();

  for (int kt = 0; kt < SEQ / 128; ++kt) {
    const int cur = (kt & 1) << 14, nxt = cur ^ 16384;
    if (kt + 1 < SEQ / 128) {     // prefetch next 128-key tile
      const size_t kofs = (size_t)(kt + 1) * 128 * DHEAD;
#pragma unroll
      for (int i = 0; i < 4; ++i) {
        gll16(pK0 + kofs + (size_t)i * 32 * DHEAD, sK + nxt + lKo0 + i * 4096);
        gll16(pV0 + kofs + (size_t)i * 32 * DHEAD, sV + nxt + lVo0 + i * 4096);
      }
    }

#pragma unroll
    for (int half = 0; half < 2; ++half) {
      const int hb_ = cur + half * 8192;
      // swapped QK^T: S^T C-layout col q=l31, row key=(r&3)+8(r>>2)+4lh (+32ksb)
      f32x16 s[2] = {};
      __builtin_amdgcn_s_setprio(1);
#pragma unroll
      for (int ksb = 0; ksb < 2; ++ksb)
#pragma unroll
        for (int kb = 0; kb < 4; ++kb) {
          bf16x8 ak = *(const bf16x8*)(sK + hb_ + swz128(ksb*32 + l31, kb*32 + lh*16));
          s[ksb] = __builtin_amdgcn_mfma_f32_32x32x16_bf16(ak, aq[kb], s[ksb], 0, 0, 0);
        }
      __builtin_amdgcn_s_setprio(0);

      // issue all 16 V transpose-reads (latency hides under softmax VALU)
      unsigned long long v0[4][2], v1[4][2];   // [kbg][db]
      const unsigned vb = vb0 + hb_;
      TRRD(v0[0][0], v1[0][0], vb, 0, 512)
      TRRD(v0[0][1], v1[0][1], vb, 256, 768)
      TRRD(v0[1][0], v1[1][0], vb, 2048, 2560)
      TRRD(v0[1][1], v1[1][1], vb, 2304, 2816)
      TRRD(v0[2][0], v1[2][0], vb, 4096, 4608)
      TRRD(v0[2][1], v1[2][1], vb, 4352, 4864)
      TRRD(v0[3][0], v1[3][0], vb, 6144, 6656)
      TRRD(v0[3][1], v1[3][1], vb, 6400, 6912)

      // P = exp2(S^T); build PV A-fragments in-register via permlane32_swap
      bf16x8 paf[4];
#pragma unroll
      for (int ksb = 0; ksb < 2; ++ksb) {
        float p[16];
#pragma unroll
        for (int r = 0; r < 16; ++r)
          p[r] = __builtin_amdgcn_exp2f(s[ksb][r]);
        unsigned a0 = pack2(p[0], p[1]),   b0 = pack2(p[4], p[5]);
        unsigned a1 = pack2(p[2], p[3]),   b1 = pack2(p[6], p[7]);
        PSWAP(a0, b0) PSWAP(a1, b1)
        unsigned c0 = pack2(p[8], p[9]),   d0 = pack2(p[12], p[13]);
        unsigned c1 = pack2(p[10], p[11]), d1 = pack2(p[14], p[15]);
        PSWAP(c0, d0) PSWAP(c1, d1)
        union { unsigned u[4]; bf16x8 v; } A0, A1;
        A0.u[0] = a0; A0.u[1] = a1; A0.u[2] = b0; A0.u[3] = b1;
        A1.u[0] = c0; A1.u[1] = c1; A1.u[2] = d0; A1.u[3] = d1;
        paf[ksb * 2 + 0] = A0.v;
        paf[ksb * 2 + 1] = A1.v;
      }

      asm volatile("s_waitcnt lgkmcnt(0)" ::: "memory");
      __builtin_amdgcn_sched_barrier(0);

      // PV: O[q][d] += P[q][key] * V[key][d]; lacc += P row-sums (ones-MFMA)
      __builtin_amdgcn_s_setprio(1);
#pragma unroll
      for (int kbg = 0; kbg < 4; ++kbg) {
#pragma unroll
        for (int db = 0; db < 2; ++db) {
          union { unsigned long long u[2]; bf16x8 v; } V;
          V.u[0] = v0[kbg][db]; V.u[1] = v1[kbg][db];
          oacc[db] = __builtin_amdgcn_mfma_f32_32x32x16_bf16(paf[kbg], V.v, oacc[db], 0, 0, 0);
        }
        lacc = __builtin_amdgcn_mfma_f32_32x32x16_bf16(paf[kbg], onesf, lacc, 0, 0, 0);
      }
      __builtin_amdgcn_s_setprio(0);
    }
    __syncthreads();   // drains prefetch vmcnt + publishes next buffer
  }

  // lacc[r] = full row-sum for q=q_r in the SAME C-layout as oacc -> no shfl.
  const int b = bh >> 4, hh = bh & 15;
#pragma unroll
  for (int r = 0; r < 16; ++r) {
    int q_r = (r & 3) + 8 * (r >> 2) + 4 * lh;
    float inv = __builtin_amdgcn_rcpf(lacc[r]);
    int row = qw + q_r;
#pragma unroll
    for (int db = 0; db < 2; ++db)
      ctx[(size_t)(b * SEQ + row) * DMODEL + hh * DHEAD + db * 32 + l31] =
          (bf16)(oacc[db][r] * inv);
  }
  if (l31 == 0) {
#pragma unroll
    for (int r = 0; r < 16; ++r) {
      int q_r = (r & 3) + 8 * (r >> 2) + 4 * lh;
      lstat[(size_t)bh * SEQ + qw + q_r] = lacc[r];
    }
  }
}

// ------- fused tail: blocks 0..511 mean (64q x 128k, head-dbuf),           --
// -------             blocks 512..1023 gemm_o (64x128 + residual)           --
__global__ __launch_bounds__(256) void tail_kernel(
    const bf16* __restrict__ Qb, const bf16* __restrict__ Kb,
    const float* __restrict__ lstat, float* __restrict__ out2,
    const bf16* __restrict__ ctx, const bf16* __restrict__ weffo,
    const float* __restrict__ bias, const float* __restrict__ resid,
    float* __restrict__ outf)
{
  __shared__ __align__(16) char smem[2 * 16384];
  const int tid = threadIdx.x, w = tid >> 6, lane = tid & 63;

  if (blockIdx.x < 512) {
    // ---------------- mean path ----------------
    char* sK = smem;
    const int bid = blockIdx.x;
    const int nb2 = (bid & 7) * 64 + (bid >> 3);
    const int b = nb2 >> 7;
    const int q0 = ((nb2 >> 3) & 15) * 64, k0 = (nb2 & 7) * 128;
    const int qw = q0 + w * 16;
    size_t goff[4]; int lofs[4];
#pragma unroll
    for (int i = 0; i < 4; ++i) {
      int chunk = i * 4 + w;
      int row = chunk * 8 + (lane >> 3);
      int ss = (lane & 7) ^ (row & 7);
      goff[i] = (size_t)(k0 + row) * DHEAD + ss * 8;
      lofs[i] = chunk * 1024;
    }
    const bf16* Kb_b = Kb + (size_t)b * NHEADS * SEQ * DHEAD;
    const bf16* Qb_b = Qb + (size_t)b * NHEADS * SEQ * DHEAD;

    f32x4 macc[8] = {};
#pragma unroll
    for (int i = 0; i < 4; ++i) gll16(Kb_b + goff[i], sK + lofs[i]);
    asm volatile("s_waitcnt vmcnt(0)" ::: "memory");
    __syncthreads();

    for (int h = 0; h < NHEADS; ++h) {
      const int cur = (h & 1) << 14, nxt = cur ^ 16384;
      if (h + 1 < NHEADS) {
        const bf16* Kn = Kb_b + (size_t)(h + 1) * SEQ * DHEAD;
#pragma unroll
        for (int i = 0; i < 4; ++i) gll16(Kn + goff[i], sK + nxt + lofs[i]);
      }
      const bf16* Qbase = Qb_b + (size_t)h * SEQ * DHEAD;
      bf16x8 aq[2];
#pragma unroll
      for (int ks = 0; ks < 2; ++ks)
        aq[ks] = *(const bf16x8*)(Qbase + (size_t)(qw + (lane & 15)) * DHEAD
                                  + ks * 32 + (lane >> 4) * 8);
      char* cK = sK + cur;
      f32x4 sc[8] = {};
#pragma unroll
      for (int ks = 0; ks < 2; ++ks)
#pragma unroll
        for (int ni = 0; ni < 8; ++ni) {
          bf16x8 bk = *(const bf16x8*)(cK + swz128(ni*16 + (lane & 15), ks*64 + (lane >> 4)*16));
          sc[ni] = __builtin_amdgcn_mfma_f32_16x16x32_bf16(aq[ks], bk, sc[ni], 0, 0, 0);
        }
      float lsc[4];
      const float* ls = lstat + ((size_t)(b * NHEADS + h)) * SEQ;
#pragma unroll
      for (int r = 0; r < 4; ++r)
        lsc[r] = 0.0625f * __builtin_amdgcn_rcpf(ls[qw + (lane >> 4)*4 + r]);
#pragma unroll
      for (int ni = 0; ni < 8; ++ni)
#pragma unroll
        for (int r = 0; r < 4; ++r)
          macc[ni][r] += __builtin_amdgcn_exp2f(sc[ni][r]) * lsc[r];
      asm volatile("s_waitcnt vmcnt(0)" ::: "memory");
      __syncthreads();
    }
#pragma unroll
    for (int r = 0; r < 4; ++r) {
      int qrow = qw + (lane >> 4) * 4 + r;
#pragma unroll
      for (int ni = 0; ni < 8; ++ni)
        out2[(size_t)(b * SEQ + qrow) * SEQ + k0 + ni * 16 + (lane & 15)] = macc[ni][r];
    }
  } else {
    // ---------------- gemm_o path ----------------
    char* sA = smem; char* sB = smem + 8192;
    const int bid = blockIdx.x - 512;
    const int nb = (bid & 7) * 64 + (bid >> 3);
    const int n0 = (nb & 7) * 128, m0 = (nb >> 3) * 64;
    const int wm = (w & 1) * 32, wn = (w >> 1) * 64;
    f32x4 acc[2][4] = {};
    const bf16* pA[2]; char* lA[2];
    const bf16* pB[4]; char* lB[4];
#pragma unroll
    for (int i = 0; i < 2; ++i) {
      int chunk = i * 4 + w;
      int row = chunk * 8 + (lane >> 3);
      int ss = (lane & 7) ^ (row & 7);
      pA[i] = ctx + (size_t)(m0 + row) * DMODEL + ss * 8;
      lA[i] = sA + chunk * 1024;
    }
#pragma unroll
    for (int i = 0; i < 4; ++i) {
      int chunk = i * 4 + w;
      int row = chunk * 8 + (lane >> 3);
      int ss = (lane & 7) ^ (row & 7);
      pB[i] = weffo + (size_t)(n0 + row) * DMODEL + ss * 8;
      lB[i] = sB + chunk * 1024;
    }
    for (int kt = 0; kt < DMODEL / 64; ++kt) {
      const int kbase = kt * 64;
#pragma unroll
      for (int i = 0; i < 2; ++i) gll16(pA[i] + kbase, lA[i]);
#pragma unroll
      for (int i = 0; i < 4; ++i) gll16(pB[i] + kbase, lB[i]);
      __syncthreads();
#pragma unroll
      for (int ks = 0; ks < 2; ++ks) {
        bf16x8 af[2], bfg[4];
#pragma unroll
        for (int mi = 0; mi < 2; ++mi)
          af[mi] = *(const bf16x8*)(sA + swz128(wm + mi*16 + (lane & 15), ks*64 + (lane >> 4)*16));
#pragma unroll
        for (int ni = 0; ni < 4; ++ni)
          bfg[ni] = *(const bf16x8*)(sB + swz128(wn + ni*16 + (lane & 15), ks*64 + (lane >> 4)*16));
#pragma unroll
        for (int mi = 0; mi < 2; ++mi)
#pragma unroll
          for (int ni = 0; ni < 4; ++ni)
            acc[mi][ni] = __builtin_amdgcn_mfma_f32_16x16x32_bf16(af[mi], bfg[ni], acc[mi][ni], 0, 0, 0);
      }
      __syncthreads();
    }
#pragma unroll
    for (int mi = 0; mi < 2; ++mi) {
#pragma unroll
      for (int ni = 0; ni < 4; ++ni) {
        int col = n0 + wn + ni * 16 + (lane & 15);
        float bcol = bias[col];
#pragma unroll
        for (int r = 0; r < 4; ++r) {
          int row = m0 + wm + mi * 16 + (lane >> 4) * 4 + r;
          outf[(size_t)row * DMODEL + col] =
              acc[mi][ni][r] + bcol + resid[(size_t)row * DMODEL + col];
        }
      }
    }
  }
}

// ---------------- residual LayerNorm (in-place on fp32 rows) ----------------
__global__ __launch_bounds__(256) void ln_kernel(
    float* __restrict__ hb, const float* __restrict__ g,
    const float* __restrict__ bvec, float* __restrict__ out)
{
  const int row = blockIdx.x, t = threadIdx.x;
  float4 v = *(const float4*)(hb + (size_t)row * DMODEL + t * 4);
  float s = v.x + v.y + v.z + v.w;
  float s2 = v.x*v.x + v.y*v.y + v.z*v.z + v.w*v.w;
#pragma unroll
  for (int off = 32; off >= 1; off >>= 1) {
    s  += __shfl_down(s, off);
    s2 += __shfl_down(s2, off);
  }
  __shared__ float red[8];
  const int w = t >> 6;
  if ((t & 63) == 0) { red[w] = s; red[4 + w] = s2; }
  __syncthreads();
  if (t == 0) {
    red[0] = red[0] + red[1] + red[2] + red[3];
    red[4] = red[4] + red[5] + red[6] + red[7];
  }
  __syncthreads();
  float mu = red[0] * (1.0f / DMODEL);
  float var = red[4] * (1.0f / DMODEL) - mu * mu;
  float rs = rsqrtf(var + 1e-5f);
  float4 gv = *(const float4*)(g + t * 4);
  float4 bv = *(const float4*)(bvec + t * 4);
  float4 o;
  o.x = (v.x - mu) * rs * gv.x + bv.x;
  o.y = (v.y - mu) * rs * gv.y + bv.y;
  o.z = (v.z - mu) * rs * gv.z + bv.z;
  o.w = (v.w - mu) * rs * gv.w + bv.w;
  *(float4*)(out + (size_t)row * DMODEL + t * 4) = o;
}

extern "C" void kernel_launch(void* const* d_in, const int* in_sizes, int n_in,
                              void* d_out, int out_size, void* d_ws, size_t ws_size,
                              hipStream_t stream) {
  (void)in_sizes; (void)n_in; (void)out_size; (void)ws_size;
  const float* x = (const float*)d_in[0];
  const float* w_[4]  = {(const float*)d_in[1],  (const float*)d_in[5],
                         (const float*)d_in[9],  (const float*)d_in[13]};
  const float* b_[4]  = {(const float*)d_in[2],  (const float*)d_in[6],
                         (const float*)d_in[10], (const float*)d_in[14]};
  const float* A_[4]  = {(const float*)d_in[3],  (const float*)d_in[7],
                         (const float*)d_in[11], (const float*)d_in[15]};
  const float* Bm_[4] = {(const float*)d_in[4],  (const float*)d_in[8],
                         (const float*)d_in[12], (const float*)d_in[16]};
  const float* lng = (const float*)d_in[17];
  const float* lnb = (const float*)d_in[18];

  char* ws = (char*)d_ws;
  bf16* xb    = (bf16*)(ws);                         // 8MB, reused as ctx later
  bf16* weff  = (bf16*)(ws + (8u  << 20));           // 4 x 2MB (q|k|v|o contiguous)
  bf16* Qb    = (bf16*)(ws + (16u << 20));           // 8MB [b][h][s][d] (pre-scaled)
  bf16* Kb    = (bf16*)(ws + (24u << 20));           // 8MB [b][h][s][d]
  bf16* Vb    = (bf16*)(ws + (32u << 20));           // 8MB [b][h][s][d]
  float* lstat = (float*)(ws + (40u << 20));         // 256KB
  bf16* ctx = xb;                    // alias: xb dead after QKV projections
  float* hbuf = (float*)d_out;       // fp32 scratch = output slot 0 (in-place LN)
  float* out2 = (float*)d_out + (size_t)MTOT * DMODEL;

  prep_kernel<<<dim3(8192), dim3(256), 0, stream>>>(
      w_[0], A_[0], Bm_[0], w_[1], A_[1], Bm_[1],
      w_[2], A_[2], Bm_[2], w_[3], A_[3], Bm_[3], weff, x, xb);

  gemm_qkv_kernel<<<dim3(512), 512, 0, stream>>>(
      xb, weff, b_[0], b_[1], b_[2], Qb, Kb, Vb);

  flash_kernel<<<dim3(512), 256, 0, stream>>>(Qb, Kb, Vb, ctx, lstat);

  tail_kernel<<<dim3(1024), 256, 0, stream>>>(
      Qb, Kb, lstat, out2,
      ctx, weff + 3u * DMODEL * DMODEL, b_[3], x, hbuf);

  ln_kernel<<<dim3(MTOT), 256, 0, stream>>>(hbuf, lng, lnb, hbuf);
}

// Round 21
// 119.561 us; speedup vs baseline: 1.0330x; 1.0061x over previous
//
#include <hip/hip_runtime.h>

#define DMODEL 1024
#define NHEADS 16
#define DHEAD  64
#define RANK   16
#define BATCH  4
#define SEQ    1024
#define MTOT   (BATCH*SEQ)   // 4096
#define QSCALE 0.18033688011112042f  // log2(e)/8 : folded into Q projection

typedef __bf16 bf16;
typedef __bf16 bf16x8 __attribute__((ext_vector_type(8)));
typedef __bf16 bf16x4 __attribute__((ext_vector_type(4)));
typedef float  f32x4  __attribute__((ext_vector_type(4)));
typedef float  f32x16 __attribute__((ext_vector_type(16)));

// Byte-offset swizzle for LDS tiles with 128B rows (16B granules).
__device__ __forceinline__ int swz128(int row, int byte_in_row) {
  int slot = byte_in_row >> 4;
  return row * 128 + (((slot ^ (row & 7)) << 4) | (byte_in_row & 15));
}

// async global->LDS, 16B per lane. lds ptr wave-uniform; HW adds lane*16.
__device__ __forceinline__ void gll16(const void* g, void* l) {
  __builtin_amdgcn_global_load_lds((const __attribute__((address_space(1))) unsigned int*)g,
                                   (__attribute__((address_space(3))) unsigned int*)l, 16, 0, 0);
}

// pack two floats to packed bf16 pair
__device__ __forceinline__ unsigned pack2(float a, float b) {
  union { bf16 h[2]; unsigned u; } x;
  x.h[0] = (bf16)a; x.h[1] = (bf16)b;
  return x.u;
}

// swap hi-32-lanes of a with lo-32-lanes of b (both regs updated)
#define PSWAP(a, b) asm volatile("v_permlane32_swap_b32 %0, %1" : "+v"(a), "+v"(b));

// two ds_read_b64_tr_b16 with literal offsets (rule 18 fence applied by caller)
#define TRRD(lo, hi, base, o0, o1)                                   \
  asm volatile("ds_read_b64_tr_b16 %0, %2 offset:" #o0 "\n\t"        \
               "ds_read_b64_tr_b16 %1, %2 offset:" #o1               \
               : "=v"(lo), "=v"(hi) : "v"(base));

// ------- fused prologue: blocks 0..4095 prep Weff, 4096..8191 cast x --------
__global__ void prep_kernel(
    const float* __restrict__ W0, const float* __restrict__ A0, const float* __restrict__ B0,
    const float* __restrict__ W1, const float* __restrict__ A1, const float* __restrict__ B1,
    const float* __restrict__ W2, const float* __restrict__ A2, const float* __restrict__ B2,
    const float* __restrict__ W3, const float* __restrict__ A3, const float* __restrict__ B3,
    bf16* __restrict__ out, const float* __restrict__ x, bf16* __restrict__ xb) {
  __shared__ float bsc[RANK];
  const int blk = blockIdx.x;
  if (blk < 4096) {
    const int l = blk >> 10;
    const float* W = l == 0 ? W0 : l == 1 ? W1 : l == 2 ? W2 : W3;
    const float* A = l == 0 ? A0 : l == 1 ? A1 : l == 2 ? A2 : A3;
    const float* Bm = l == 0 ? B0 : l == 1 ? B1 : l == 2 ? B2 : B3;
    bf16* o = out + (size_t)l * DMODEL * DMODEL;
    const int n = blk & 1023;
    if (threadIdx.x < RANK) bsc[threadIdx.x] = Bm[threadIdx.x * DMODEL + n] * 2.0f;
    __syncthreads();
    float br[RANK];
#pragma unroll
    for (int r = 0; r < RANK; ++r) br[r] = bsc[r];
    for (int k0 = 0; k0 < DMODEL; k0 += 256) {
      int k = k0 + threadIdx.x;
      float acc = W[n * DMODEL + k];
      const float4* arow = (const float4*)(A + k * RANK);
#pragma unroll
      for (int r4 = 0; r4 < 4; ++r4) {
        float4 a = arow[r4];
        acc += a.x*br[r4*4+0] + a.y*br[r4*4+1] + a.z*br[r4*4+2] + a.w*br[r4*4+3];
      }
      o[n * DMODEL + k] = (bf16)acc;
    }
  } else {
    int i = ((blk - 4096) * 256 + threadIdx.x) * 4;
    float4 v = *(const float4*)(x + i);
    bf16x4 o4 = { (bf16)v.x, (bf16)v.y, (bf16)v.z, (bf16)v.w };
    *(bf16x4*)(xb + i) = o4;
  }
}

// QKV fused over N=3072: 128x192 tile, 8 waves (2x4 grid, 64x48 per wave).
// Grid 512 = exactly 2 blocks/CU. Double-buffered staging, ONE barrier per
// K-tile (flash-proven recipe): prefetch kt+1 -> compute kt -> barrier.
// LDS 80KB dbuf still fits 2 blocks/CU (160/80 = 2) -> zero occupancy cost.
__global__ __launch_bounds__(512) void gemm_qkv_kernel(
    const bf16* __restrict__ xb, const bf16* __restrict__ weff,
    const float* __restrict__ bq, const float* __restrict__ bk, const float* __restrict__ bv,
    bf16* __restrict__ Qb, bf16* __restrict__ Kb, bf16* __restrict__ Vb)
{
  __shared__ __align__(16) char sA[2 * 16384];   // dbuf 128 rows x 64 bf16
  __shared__ __align__(16) char sB[2 * 24576];   // dbuf 192 rows x 64 bf16
  const int tid = threadIdx.x, w = tid >> 6, lane = tid & 63;
  // XCD-chunked swizzle: 512 blocks -> 64 consecutive per XCD (bijective)
  const int bid = blockIdx.x;
  const int nb = (bid & 7) * 64 + (bid >> 3);
  const int n0 = (nb & 15) * 192, m0 = (nb >> 4) * 128;
  const int wm = (w & 1) * 64, wn = (w >> 1) * 48;
  f32x4 acc[4][3] = {};

  const bf16* pA[2]; const bf16* pB[3]; int lAo[2], lBo[3];
#pragma unroll
  for (int i = 0; i < 2; ++i) {
    int ci = i * 8 + w;
    int row = ci * 8 + (lane >> 3);
    int ss = (lane & 7) ^ (row & 7);
    pA[i] = xb + (size_t)(m0 + row) * DMODEL + ss * 8;
    lAo[i] = ci * 1024;
  }
#pragma unroll
  for (int i = 0; i < 3; ++i) {
    int ci = i * 8 + w;
    int row = ci * 8 + (lane >> 3);
    int ss = (lane & 7) ^ (row & 7);
    pB[i] = weff + (size_t)(n0 + row) * DMODEL + ss * 8;
    lBo[i] = ci * 1024;
  }

  // prologue: stage K-tile 0 into buffer 0
#pragma unroll
  for (int i = 0; i < 2; ++i) gll16(pA[i], sA + lAo[i]);
#pragma unroll
  for (int i = 0; i < 3; ++i) gll16(pB[i], sB + lBo[i]);
  __syncthreads();

  for (int kt = 0; kt < DMODEL / 64; ++kt) {
    const int curA = (kt & 1) * 16384, nxtA = curA ^ 16384;
    const int curB = (kt & 1) * 24576, nxtB = curB ^ 24576;
    if (kt + 1 < DMODEL / 64) {    // prefetch next tile; drains at loop barrier
      const int kb = (kt + 1) * 64;
#pragma unroll
      for (int i = 0; i < 2; ++i) gll16(pA[i] + kb, sA + nxtA + lAo[i]);
#pragma unroll
      for (int i = 0; i < 3; ++i) gll16(pB[i] + kb, sB + nxtB + lBo[i]);
    }
#pragma unroll
    for (int ks = 0; ks < 2; ++ks) {
      bf16x8 af[4], bfg[3];
#pragma unroll
      for (int mi = 0; mi < 4; ++mi)
        af[mi] = *(const bf16x8*)(sA + curA + swz128(wm + mi*16 + (lane & 15), ks*64 + (lane >> 4)*16));
#pragma unroll
      for (int ni = 0; ni < 3; ++ni)
        bfg[ni] = *(const bf16x8*)(sB + curB + swz128(wn + ni*16 + (lane & 15), ks*64 + (lane >> 4)*16));
#pragma unroll
      for (int mi = 0; mi < 4; ++mi)
#pragma unroll
        for (int ni = 0; ni < 3; ++ni)
          acc[mi][ni] = __builtin_amdgcn_mfma_f32_16x16x32_bf16(af[mi], bfg[ni], acc[mi][ni], 0, 0, 0);
    }
    __syncthreads();   // drains prefetch + publishes next buffer
  }

  // Epilogue: 16-aligned fragment never straddles a 1024 boundary -> per-ni z.
#pragma unroll
  for (int mi = 0; mi < 4; ++mi) {
#pragma unroll
    for (int ni = 0; ni < 3; ++ni) {
      int col = n0 + wn + ni * 16 + (lane & 15);      // global over 3072
      int zc = col >> 10;
      const float* bz = zc == 0 ? bq : (zc == 1 ? bk : bv);
      bf16* outp = zc == 0 ? Qb : (zc == 1 ? Kb : Vb);
      float scl = zc == 0 ? QSCALE : 1.0f;
      float bcol = bz[col & 1023];
      int h = (col >> 6) & 15, d = col & 63;
#pragma unroll
      for (int r = 0; r < 4; ++r) {
        int row = m0 + wm + mi * 16 + (lane >> 4) * 4 + r;
        float v = (acc[mi][ni][r] + bcol) * scl;
        int b = row >> 10, s = row & 1023;
        outp[(size_t)((b * NHEADS + h) * SEQ + s) * DHEAD + d] = (bf16)v;
      }
    }
  }
}

// -------- flash attention: 32x32 swapped-QK, in-register P via permlane -----
// KVBLK=128 (two 64-key halves per k-tile). lsum via ones-MFMA (C-layout).
// 4 waves x 32q = QBLK 128; grid 512 (2 blocks/CU; LDS 64KB dbuf).
__global__ __launch_bounds__(256) void flash_kernel(
    const bf16* __restrict__ Qb, const bf16* __restrict__ Kb, const bf16* __restrict__ Vb,
    bf16* __restrict__ ctx, float* __restrict__ lstat)
{
  __shared__ __align__(16) char sK[2 * 16384];  // dbuf [128 key][128B d] swizzled
  __shared__ __align__(16) char sV[2 * 16384];  // dbuf subtiled [k/4][d/16][4][16]
  const int tid = threadIdx.x, w = tid >> 6, lane = tid & 63;
  const int l31 = lane & 31, lh = lane >> 5;
  const int bid = blockIdx.x;
  const int nb = (bid & 7) * 64 + (bid >> 3);
  const int bh = nb >> 3;
  const int q0 = (nb & 7) * 128;
  const bf16* Qbase = Qb + (size_t)bh * SEQ * DHEAD;
  const bf16* Kbase = Kb + (size_t)bh * SEQ * DHEAD;
  const bf16* Vbase = Vb + (size_t)bh * SEQ * DHEAD;
  const int qw = q0 + w * 32;

  // Q fragments (B-operand): lane l -> Q[q=qw+l31][kd = kb*16 + lh*8 + j]
  bf16x8 aq[4];
#pragma unroll
  for (int kb = 0; kb < 4; ++kb)
    aq[kb] = *(const bf16x8*)(Qbase + (size_t)(qw + l31) * DHEAD + kb * 16 + lh * 8);

  // ones B-fragment for row-sum MFMA
  bf16x8 onesf;
#pragma unroll
  for (int j = 0; j < 8; ++j) onesf[j] = (bf16)1.0f;

  // staging: wave stages chunks {w, w+4, w+8, w+12} for K and V.
  const bf16* pK0; const bf16* pV0; int lKo0, lVo0;
  {
    int rowK = w * 8 + (lane >> 3);
    int ssK = (lane & 7) ^ (rowK & 7);
    pK0 = Kbase + (size_t)rowK * DHEAD + ssK * 8;   // + kt*128*DHEAD
    lKo0 = w * 1024;
    int kV = w * 8 + ((lane >> 5) & 1) * 4 + ((lane >> 1) & 3);
    int dV = (((lane >> 3) & 3) << 4) + ((lane & 1) << 3);
    pV0 = Vbase + (size_t)kV * DHEAD + dV;          // + kt*128*DHEAD
    lVo0 = w * 1024;
  }

  // V tr-read base (validated): per-lane = lh*1024 + bit4*128 + (l&15)*8
  const unsigned vb0 = (unsigned)(uintptr_t)sV + lh * 1024 + ((lane >> 4) & 1) * 128
                       + (lane & 15) * 8;

  f32x16 oacc[2] = {};
  f32x16 lacc = {};

  // prologue: stage k-tile 0 (128 keys) into buffer 0
#pragma unroll
  for (int i = 0; i < 4; ++i) {
    gll16(pK0 + (size_t)i * 32 * DHEAD, sK + lKo0 + i * 4096);
    gll16(pV0 + (size_t)i * 32 * DHEAD, sV + lVo0 + i * 4096);
  }
  __syncthreads();

  for (int kt = 0; kt < SEQ / 128; ++kt) {
    const int cur = (kt & 1) << 14, nxt = cur ^ 16384;
    if (kt + 1 < SEQ / 128) {     // prefetch next 128-key tile
      const size_t kofs = (size_t)(kt + 1) * 128 * DHEAD;
#pragma unroll
      for (int i = 0; i < 4; ++i) {
        gll16(pK0 + kofs + (size_t)i * 32 * DHEAD, sK + nxt + lKo0 + i * 4096);
        gll16(pV0 + kofs + (size_t)i * 32 * DHEAD, sV + nxt + lVo0 + i * 4096);
      }
    }

#pragma unroll
    for (int half = 0; half < 2; ++half) {
      const int hb_ = cur + half * 8192;
      // swapped QK^T: S^T C-layout col q=l31, row key=(r&3)+8(r>>2)+4lh (+32ksb)
      f32x16 s[2] = {};
      __builtin_amdgcn_s_setprio(1);
#pragma unroll
      for (int ksb = 0; ksb < 2; ++ksb)
#pragma unroll
        for (int kb = 0; kb < 4; ++kb) {
          bf16x8 ak = *(const bf16x8*)(sK + hb_ + swz128(ksb*32 + l31, kb*32 + lh*16));
          s[ksb] = __builtin_amdgcn_mfma_f32_32x32x16_bf16(ak, aq[kb], s[ksb], 0, 0, 0);
        }
      __builtin_amdgcn_s_setprio(0);

      // issue all 16 V transpose-reads (latency hides under softmax VALU)
      unsigned long long v0[4][2], v1[4][2];   // [kbg][db]
      const unsigned vb = vb0 + hb_;
      TRRD(v0[0][0], v1[0][0], vb, 0, 512)
      TRRD(v0[0][1], v1[0][1], vb, 256, 768)
      TRRD(v0[1][0], v1[1][0], vb, 2048, 2560)
      TRRD(v0[1][1], v1[1][1], vb, 2304, 2816)
      TRRD(v0[2][0], v1[2][0], vb, 4096, 4608)
      TRRD(v0[2][1], v1[2][1], vb, 4352, 4864)
      TRRD(v0[3][0], v1[3][0], vb, 6144, 6656)
      TRRD(v0[3][1], v1[3][1], vb, 6400, 6912)

      // P = exp2(S^T); build PV A-fragments in-register via permlane32_swap
      bf16x8 paf[4];
#pragma unroll
      for (int ksb = 0; ksb < 2; ++ksb) {
        float p[16];
#pragma unroll
        for (int r = 0; r < 16; ++r)
          p[r] = __builtin_amdgcn_exp2f(s[ksb][r]);
        unsigned a0 = pack2(p[0], p[1]),   b0 = pack2(p[4], p[5]);
        unsigned a1 = pack2(p[2], p[3]),   b1 = pack2(p[6], p[7]);
        PSWAP(a0, b0) PSWAP(a1, b1)
        unsigned c0 = pack2(p[8], p[9]),   d0 = pack2(p[12], p[13]);
        unsigned c1 = pack2(p[10], p[11]), d1 = pack2(p[14], p[15]);
        PSWAP(c0, d0) PSWAP(c1, d1)
        union { unsigned u[4]; bf16x8 v; } A0, A1;
        A0.u[0] = a0; A0.u[1] = a1; A0.u[2] = b0; A0.u[3] = b1;
        A1.u[0] = c0; A1.u[1] = c1; A1.u[2] = d0; A1.u[3] = d1;
        paf[ksb * 2 + 0] = A0.v;
        paf[ksb * 2 + 1] = A1.v;
      }

      asm volatile("s_waitcnt lgkmcnt(0)" ::: "memory");
      __builtin_amdgcn_sched_barrier(0);

      // PV: O[q][d] += P[q][key] * V[key][d]; lacc += P row-sums (ones-MFMA)
      __builtin_amdgcn_s_setprio(1);
#pragma unroll
      for (int kbg = 0; kbg < 4; ++kbg) {
#pragma unroll
        for (int db = 0; db < 2; ++db) {
          union { unsigned long long u[2]; bf16x8 v; } V;
          V.u[0] = v0[kbg][db]; V.u[1] = v1[kbg][db];
          oacc[db] = __builtin_amdgcn_mfma_f32_32x32x16_bf16(paf[kbg], V.v, oacc[db], 0, 0, 0);
        }
        lacc = __builtin_amdgcn_mfma_f32_32x32x16_bf16(paf[kbg], onesf, lacc, 0, 0, 0);
      }
      __builtin_amdgcn_s_setprio(0);
    }
    __syncthreads();   // drains prefetch vmcnt + publishes next buffer
  }

  // lacc[r] = full row-sum for q=q_r in the SAME C-layout as oacc -> no shfl.
  const int b = bh >> 4, hh = bh & 15;
#pragma unroll
  for (int r = 0; r < 16; ++r) {
    int q_r = (r & 3) + 8 * (r >> 2) + 4 * lh;
    float inv = __builtin_amdgcn_rcpf(lacc[r]);
    int row = qw + q_r;
#pragma unroll
    for (int db = 0; db < 2; ++db)
      ctx[(size_t)(b * SEQ + row) * DMODEL + hh * DHEAD + db * 32 + l31] =
          (bf16)(oacc[db][r] * inv);
  }
  if (l31 == 0) {
#pragma unroll
    for (int r = 0; r < 16; ++r) {
      int q_r = (r & 3) + 8 * (r >> 2) + 4 * lh;
      lstat[(size_t)bh * SEQ + qw + q_r] = lacc[r];
    }
  }
}

// ------- fused tail: blocks 0..511 mean (64q x 128k, head-dbuf),           --
// -------             blocks 512..1023 gemm_o (64x128 + residual)           --
__global__ __launch_bounds__(256) void tail_kernel(
    const bf16* __restrict__ Qb, const bf16* __restrict__ Kb,
    const float* __restrict__ lstat, float* __restrict__ out2,
    const bf16* __restrict__ ctx, const bf16* __restrict__ weffo,
    const float* __restrict__ bias, const float* __restrict__ resid,
    float* __restrict__ outf)
{
  __shared__ __align__(16) char smem[2 * 16384];
  const int tid = threadIdx.x, w = tid >> 6, lane = tid & 63;

  if (blockIdx.x < 512) {
    // ---------------- mean path ----------------
    char* sK = smem;
    const int bid = blockIdx.x;
    const int nb2 = (bid & 7) * 64 + (bid >> 3);
    const int b = nb2 >> 7;
    const int q0 = ((nb2 >> 3) & 15) * 64, k0 = (nb2 & 7) * 128;
    const int qw = q0 + w * 16;
    size_t goff[4]; int lofs[4];
#pragma unroll
    for (int i = 0; i < 4; ++i) {
      int chunk = i * 4 + w;
      int row = chunk * 8 + (lane >> 3);
      int ss = (lane & 7) ^ (row & 7);
      goff[i] = (size_t)(k0 + row) * DHEAD + ss * 8;
      lofs[i] = chunk * 1024;
    }
    const bf16* Kb_b = Kb + (size_t)b * NHEADS * SEQ * DHEAD;
    const bf16* Qb_b = Qb + (size_t)b * NHEADS * SEQ * DHEAD;

    f32x4 macc[8] = {};
#pragma unroll
    for (int i = 0; i < 4; ++i) gll16(Kb_b + goff[i], sK + lofs[i]);
    asm volatile("s_waitcnt vmcnt(0)" ::: "memory");
    __syncthreads();

    for (int h = 0; h < NHEADS; ++h) {
      const int cur = (h & 1) << 14, nxt = cur ^ 16384;
      if (h + 1 < NHEADS) {
        const bf16* Kn = Kb_b + (size_t)(h + 1) * SEQ * DHEAD;
#pragma unroll
        for (int i = 0; i < 4; ++i) gll16(Kn + goff[i], sK + nxt + lofs[i]);
      }
      const bf16* Qbase = Qb_b + (size_t)h * SEQ * DHEAD;
      bf16x8 aq[2];
#pragma unroll
      for (int ks = 0; ks < 2; ++ks)
        aq[ks] = *(const bf16x8*)(Qbase + (size_t)(qw + (lane & 15)) * DHEAD
                                  + ks * 32 + (lane >> 4) * 8);
      char* cK = sK + cur;
      f32x4 sc[8] = {};
#pragma unroll
      for (int ks = 0; ks < 2; ++ks)
#pragma unroll
        for (int ni = 0; ni < 8; ++ni) {
          bf16x8 bk = *(const bf16x8*)(cK + swz128(ni*16 + (lane & 15), ks*64 + (lane >> 4)*16));
          sc[ni] = __builtin_amdgcn_mfma_f32_16x16x32_bf16(aq[ks], bk, sc[ni], 0, 0, 0);
        }
      float lsc[4];
      const float* ls = lstat + ((size_t)(b * NHEADS + h)) * SEQ;
#pragma unroll
      for (int r = 0; r < 4; ++r)
        lsc[r] = 0.0625f * __builtin_amdgcn_rcpf(ls[qw + (lane >> 4)*4 + r]);
#pragma unroll
      for (int ni = 0; ni < 8; ++ni)
#pragma unroll
        for (int r = 0; r < 4; ++r)
          macc[ni][r] += __builtin_amdgcn_exp2f(sc[ni][r]) * lsc[r];
      asm volatile("s_waitcnt vmcnt(0)" ::: "memory");
      __syncthreads();
    }
#pragma unroll
    for (int r = 0; r < 4; ++r) {
      int qrow = qw + (lane >> 4) * 4 + r;
#pragma unroll
      for (int ni = 0; ni < 8; ++ni)
        out2[(size_t)(b * SEQ + qrow) * SEQ + k0 + ni * 16 + (lane & 15)] = macc[ni][r];
    }
  } else {
    // ---------------- gemm_o path ----------------
    char* sA = smem; char* sB = smem + 8192;
    const int bid = blockIdx.x - 512;
    const int nb = (bid & 7) * 64 + (bid >> 3);
    const int n0 = (nb & 7) * 128, m0 = (nb >> 3) * 64;
    const int wm = (w & 1) * 32, wn = (w >> 1) * 64;
    f32x4 acc[2][4] = {};
    const bf16* pA[2]; char* lA[2];
    const bf16* pB[4]; char* lB[4];
#pragma unroll
    for (int i = 0; i < 2; ++i) {
      int chunk = i * 4 + w;
      int row = chunk * 8 + (lane >> 3);
      int ss = (lane & 7) ^ (row & 7);
      pA[i] = ctx + (size_t)(m0 + row) * DMODEL + ss * 8;
      lA[i] = sA + chunk * 1024;
    }
#pragma unroll
    for (int i = 0; i < 4; ++i) {
      int chunk = i * 4 + w;
      int row = chunk * 8 + (lane >> 3);
      int ss = (lane & 7) ^ (row & 7);
      pB[i] = weffo + (size_t)(n0 + row) * DMODEL + ss * 8;
      lB[i] = sB + chunk * 1024;
    }
    for (int kt = 0; kt < DMODEL / 64; ++kt) {
      const int kbase = kt * 64;
#pragma unroll
      for (int i = 0; i < 2; ++i) gll16(pA[i] + kbase, lA[i]);
#pragma unroll
      for (int i = 0; i < 4; ++i) gll16(pB[i] + kbase, lB[i]);
      __syncthreads();
#pragma unroll
      for (int ks = 0; ks < 2; ++ks) {
        bf16x8 af[2], bfg[4];
#pragma unroll
        for (int mi = 0; mi < 2; ++mi)
          af[mi] = *(const bf16x8*)(sA + swz128(wm + mi*16 + (lane & 15), ks*64 + (lane >> 4)*16));
#pragma unroll
        for (int ni = 0; ni < 4; ++ni)
          bfg[ni] = *(const bf16x8*)(sB + swz128(wn + ni*16 + (lane & 15), ks*64 + (lane >> 4)*16));
#pragma unroll
        for (int mi = 0; mi < 2; ++mi)
#pragma unroll
          for (int ni = 0; ni < 4; ++ni)
            acc[mi][ni] = __builtin_amdgcn_mfma_f32_16x16x32_bf16(af[mi], bfg[ni], acc[mi][ni], 0, 0, 0);
      }
      __syncthreads();
    }
#pragma unroll
    for (int mi = 0; mi < 2; ++mi) {
#pragma unroll
      for (int ni = 0; ni < 4; ++ni) {
        int col = n0 + wn + ni * 16 + (lane & 15);
        float bcol = bias[col];
#pragma unroll
        for (int r = 0; r < 4; ++r) {
          int row = m0 + wm + mi * 16 + (lane >> 4) * 4 + r;
          outf[(size_t)row * DMODEL + col] =
              acc[mi][ni][r] + bcol + resid[(size_t)row * DMODEL + col];
        }
      }
    }
  }
}

// ---------------- residual LayerNorm (in-place on fp32 rows) ----------------
__global__ __launch_bounds__(256) void ln_kernel(
    float* __restrict__ hb, const float* __restrict__ g,
    const float* __restrict__ bvec, float* __restrict__ out)
{
  const int row = blockIdx.x, t = threadIdx.x;
  float4 v = *(const float4*)(hb + (size_t)row * DMODEL + t * 4);
  float s = v.x + v.y + v.z + v.w;
  float s2 = v.x*v.x + v.y*v.y + v.z*v.z + v.w*v.w;
#pragma unroll
  for (int off = 32; off >= 1; off >>= 1) {
    s  += __shfl_down(s, off);
    s2 += __shfl_down(s2, off);
  }
  __shared__ float red[8];
  const int w = t >> 6;
  if ((t & 63) == 0) { red[w] = s; red[4 + w] = s2; }
  __syncthreads();
  if (t == 0) {
    red[0] = red[0] + red[1] + red[2] + red[3];
    red[4] = red[4] + red[5] + red[6] + red[7];
  }
  __syncthreads();
  float mu = red[0] * (1.0f / DMODEL);
  float var = red[4] * (1.0f / DMODEL) - mu * mu;
  float rs = rsqrtf(var + 1e-5f);
  float4 gv = *(const float4*)(g + t * 4);
  float4 bv = *(const float4*)(bvec + t * 4);
  float4 o;
  o.x = (v.x - mu) * rs * gv.x + bv.x;
  o.y = (v.y - mu) * rs * gv.y + bv.y;
  o.z = (v.z - mu) * rs * gv.z + bv.z;
  o.w = (v.w - mu) * rs * gv.w + bv.w;
  *(float4*)(out + (size_t)row * DMODEL + t * 4) = o;
}

extern "C" void kernel_launch(void* const* d_in, const int* in_sizes, int n_in,
                              void* d_out, int out_size, void* d_ws, size_t ws_size,
                              hipStream_t stream) {
  (void)in_sizes; (void)n_in; (void)out_size; (void)ws_size;
  const float* x = (const float*)d_in[0];
  const float* w_[4]  = {(const float*)d_in[1],  (const float*)d_in[5],
                         (const float*)d_in[9],  (const float*)d_in[13]};
  const float* b_[4]  = {(const float*)d_in[2],  (const float*)d_in[6],
                         (const float*)d_in[10], (const float*)d_in[14]};
  const float* A_[4]  = {(const float*)d_in[3],  (const float*)d_in[7],
                         (const float*)d_in[11], (const float*)d_in[15]};
  const float* Bm_[4] = {(const float*)d_in[4],  (const float*)d_in[8],
                         (const float*)d_in[12], (const float*)d_in[16]};
  const float* lng = (const float*)d_in[17];
  const float* lnb = (const float*)d_in[18];

  char* ws = (char*)d_ws;
  bf16* xb    = (bf16*)(ws);                         // 8MB, reused as ctx later
  bf16* weff  = (bf16*)(ws + (8u  << 20));           // 4 x 2MB (q|k|v|o contiguous)
  bf16* Qb    = (bf16*)(ws + (16u << 20));           // 8MB [b][h][s][d] (pre-scaled)
  bf16* Kb    = (bf16*)(ws + (24u << 20));           // 8MB [b][h][s][d]
  bf16* Vb    = (bf16*)(ws + (32u << 20));           // 8MB [b][h][s][d]
  float* lstat = (float*)(ws + (40u << 20));         // 256KB
  bf16* ctx = xb;                    // alias: xb dead after QKV projections
  float* hbuf = (float*)d_out;       // fp32 scratch = output slot 0 (in-place LN)
  float* out2 = (float*)d_out + (size_t)MTOT * DMODEL;

  prep_kernel<<<dim3(8192), dim3(256), 0, stream>>>(
      w_[0], A_[0], Bm_[0], w_[1], A_[1], Bm_[1],
      w_[2], A_[2], Bm_[2], w_[3], A_[3], Bm_[3], weff, x, xb);

  gemm_qkv_kernel<<<dim3(512), 512, 0, stream>>>(
      xb, weff, b_[0], b_[1], b_[2], Qb, Kb, Vb);

  flash_kernel<<<dim3(512), 256, 0, stream>>>(Qb, Kb, Vb, ctx, lstat);

  tail_kernel<<<dim3(1024), 256, 0, stream>>>(
      Qb, Kb, lstat, out2,
      ctx, weff + 3u * DMODEL * DMODEL, b_[3], x, hbuf);

  ln_kernel<<<dim3(MTOT), 256, 0, stream>>>(hbuf, lng, lnb, hbuf);
}